// Round 1
// baseline (1126.694 us; speedup 1.0000x reference)
//
#include <hip/hip_runtime.h>

#define N_NODES 100000
#define N_EDGES 1600000
#define HDIM 64

// ---------------- degree computation ----------------
__global__ void degree_kernel(const int* __restrict__ src, const int* __restrict__ dst,
                              int* __restrict__ deg_out, int* __restrict__ deg_in, int E) {
    int e = blockIdx.x * blockDim.x + threadIdx.x;
    if (e < E) {
        atomicAdd(&deg_out[src[e]], 1);
        atomicAdd(&deg_in[dst[e]], 1);
    }
}

__global__ void invsqrt_kernel(const int* __restrict__ deg_out, const int* __restrict__ deg_in,
                               float* __restrict__ inv_out, float* __restrict__ inv_in, int n) {
    int i = blockIdx.x * blockDim.x + threadIdx.x;
    if (i < n) {
        float o = (float)max(deg_out[i], 1);
        float d = (float)max(deg_in[i], 1);
        inv_out[i] = 1.0f / sqrtf(o);
        inv_in[i]  = 1.0f / sqrtf(d);
    }
}

// ---------------- edge scatter: agg[dst] += h[src] * inv_out[src] ----------------
// one 64-lane wave per edge; lane = feature channel (coalesced)
__global__ void scatter_kernel(const float* __restrict__ h, const float* __restrict__ inv_out,
                               const int* __restrict__ src, const int* __restrict__ dst,
                               float* __restrict__ agg, int E) {
    long long idx = (long long)blockIdx.x * blockDim.x + threadIdx.x;
    int e = (int)(idx >> 6);
    int lane = (int)(idx & 63);
    if (e < E) {
        int s = src[e];
        int d = dst[e];
        float v = h[(long long)s * HDIM + lane] * inv_out[s];
        atomicAdd(&agg[(long long)d * HDIM + lane], v);
    }
}

// ---------------- dense: out = relu(agg * inv_in @ W + b) ----------------
// one wave per row; W staged in LDS; a[i][k] broadcast via shfl
__global__ void dense_relu_kernel(const float* __restrict__ agg, const float* __restrict__ inv_in,
                                  const float* __restrict__ W, const float* __restrict__ b,
                                  float* __restrict__ out, int n) {
    __shared__ float Wlds[HDIM * HDIM];
    int t = threadIdx.x;
    for (int i = t; i < HDIM * HDIM; i += blockDim.x) Wlds[i] = W[i];
    __syncthreads();

    int wave = t >> 6;
    int lane = t & 63;
    int row = blockIdx.x * 4 + wave;
    if (row >= n) return;

    float a = agg[(long long)row * HDIM + lane] * inv_in[row];
    float acc = 0.0f;
#pragma unroll
    for (int k = 0; k < HDIM; ++k) {
        float av = __shfl(a, k, 64);
        acc = fmaf(av, Wlds[k * HDIM + lane], acc);
    }
    acc += b[lane];
    out[(long long)row * HDIM + lane] = fmaxf(acc, 0.0f);
}

extern "C" void kernel_launch(void* const* d_in, const int* in_sizes, int n_in,
                              void* d_out, int out_size, void* d_ws, size_t ws_size,
                              hipStream_t stream) {
    const float* features = (const float*)d_in[0];   // [N, 64]
    const float* W        = (const float*)d_in[1];   // [64, 64]
    const float* b        = (const float*)d_in[2];   // [64]
    const int*   src      = (const int*)d_in[3];     // [E]
    const int*   dst      = (const int*)d_in[4];     // [E]

    float* out = (float*)d_out;                      // [N, 64]

    // workspace layout (floats)
    float* ws      = (float*)d_ws;
    float* inv_out = ws;                             // N
    float* inv_in  = ws + N_NODES;                   // N
    int*   deg_out = (int*)(ws + 2 * N_NODES);       // N
    int*   deg_in  = (int*)(ws + 3 * N_NODES);       // N
    float* agg     = ws + 4 * N_NODES;               // N*H

    const int E = N_EDGES;
    const int N = N_NODES;

    // degrees
    hipMemsetAsync(deg_out, 0, 2 * N_NODES * sizeof(int), stream);
    degree_kernel<<<(E + 255) / 256, 256, 0, stream>>>(src, dst, deg_out, deg_in, E);
    invsqrt_kernel<<<(N + 255) / 256, 256, 0, stream>>>(deg_out, deg_in, inv_out, inv_in, N);

    long long scat_threads = (long long)E * 64;
    int scat_blocks = (int)((scat_threads + 255) / 256);
    int dense_blocks = (N + 3) / 4;

    // layer 1: features -> out (temp)
    hipMemsetAsync(agg, 0, (size_t)N * HDIM * sizeof(float), stream);
    scatter_kernel<<<scat_blocks, 256, 0, stream>>>(features, inv_out, src, dst, agg, E);
    dense_relu_kernel<<<dense_blocks, 256, 0, stream>>>(agg, inv_in, W, b, out, N);

    // layer 2: out (temp) -> out
    hipMemsetAsync(agg, 0, (size_t)N * HDIM * sizeof(float), stream);
    scatter_kernel<<<scat_blocks, 256, 0, stream>>>(out, inv_out, src, dst, agg, E);
    dense_relu_kernel<<<dense_blocks, 256, 0, stream>>>(agg, inv_in, W, b, out, N);
}

// Round 2
// 697.970 us; speedup vs baseline: 1.6142x; 1.6142x over previous
//
#include <hip/hip_runtime.h>

#define N_NODES 100000
#define N_EDGES 1600000
#define HDIM 64
#define SCAN_BS 256
#define NBLK ((N_NODES + SCAN_BS - 1) / SCAN_BS)   // 391

// ---------------- degree computation ----------------
__global__ void degree_kernel(const int* __restrict__ src, const int* __restrict__ dst,
                              int* __restrict__ deg_out, int* __restrict__ deg_in, int E) {
    int e = blockIdx.x * blockDim.x + threadIdx.x;
    if (e < E) {
        atomicAdd(&deg_out[src[e]], 1);
        atomicAdd(&deg_in[dst[e]], 1);
    }
}

__global__ void invsqrt_kernel(const int* __restrict__ deg_out, const int* __restrict__ deg_in,
                               float* __restrict__ inv_out, float* __restrict__ inv_in, int n) {
    int i = blockIdx.x * blockDim.x + threadIdx.x;
    if (i < n) {
        inv_out[i] = rsqrtf((float)max(deg_out[i], 1));
        inv_in[i]  = rsqrtf((float)max(deg_in[i], 1));
    }
}

// ---------------- scan (exclusive prefix sum of deg_in -> CSR offsets) ----------------
__global__ void blocksum_kernel(const int* __restrict__ deg_in, int* __restrict__ bs) {
    int t = threadIdx.x, b = blockIdx.x;
    int i = b * SCAN_BS + t;
    int v = (i < N_NODES) ? deg_in[i] : 0;
    for (int off = 32; off > 0; off >>= 1) v += __shfl_down(v, off, 64);
    __shared__ int w[4];
    if ((t & 63) == 0) w[t >> 6] = v;
    __syncthreads();
    if (t == 0) bs[b] = w[0] + w[1] + w[2] + w[3];
}

__global__ void scan_blocksums(const int* __restrict__ bs, int* __restrict__ boff,
                               int* __restrict__ offsets) {
    __shared__ int s[512];
    int t = threadIdx.x;
    int v = (t < NBLK) ? bs[t] : 0;
    s[t] = v;
    __syncthreads();
    for (int off = 1; off < 512; off <<= 1) {
        int x = (t >= off) ? s[t - off] : 0;
        __syncthreads();
        s[t] += x;
        __syncthreads();
    }
    if (t < NBLK) boff[t] = s[t] - v;
    if (t == 0) offsets[N_NODES] = N_EDGES;  // every edge has a dst
}

__global__ void scan_final(const int* __restrict__ deg_in, const int* __restrict__ boff,
                           int* __restrict__ offsets, int* __restrict__ cursor) {
    __shared__ int s[SCAN_BS];
    int t = threadIdx.x, b = blockIdx.x;
    int i = b * SCAN_BS + t;
    int v = (i < N_NODES) ? deg_in[i] : 0;
    s[t] = v;
    __syncthreads();
    for (int off = 1; off < SCAN_BS; off <<= 1) {
        int x = (t >= off) ? s[t - off] : 0;
        __syncthreads();
        s[t] += x;
        __syncthreads();
    }
    if (i < N_NODES) {
        int excl = s[t] - v + boff[b];
        offsets[i] = excl;
        cursor[i] = excl;
    }
}

// ---------------- CSR fill: csr_src[slot of dst] = src ----------------
__global__ void fill_csr(const int* __restrict__ src, const int* __restrict__ dst,
                         int* __restrict__ cursor, int* __restrict__ csr_src, int E) {
    int e = blockIdx.x * blockDim.x + threadIdx.x;
    if (e < E) {
        int pos = atomicAdd(&cursor[dst[e]], 1);
        csr_src[pos] = src[e];
    }
}

// ---------------- fused layer: gather + normalize + dense + relu ----------------
// one wave per dst node; lane = feature channel. W staged in LDS.
__global__ void gcn_layer(const float* __restrict__ h, const float* __restrict__ inv_out,
                          const float* __restrict__ inv_in, const int* __restrict__ offsets,
                          const int* __restrict__ csr_src, const float* __restrict__ W,
                          const float* __restrict__ bias, float* __restrict__ out, int n) {
    __shared__ float Wlds[HDIM * HDIM];
    int t = threadIdx.x;
    for (int i = t; i < HDIM * HDIM; i += blockDim.x) Wlds[i] = W[i];
    __syncthreads();

    int wave = t >> 6;
    int lane = t & 63;
    int row = blockIdx.x * 4 + wave;
    if (row >= n) return;

    int start = offsets[row];
    int end   = offsets[row + 1];

    float acc = 0.0f;
    for (int j = start; j < end; j += 64) {
        int m = end - j;
        if (m > 64) m = 64;
        int   sidx = 0;
        float sc   = 0.0f;
        if (lane < m) {
            sidx = csr_src[j + lane];
            sc   = inv_out[sidx];
        }
#pragma unroll 4
        for (int jj = 0; jj < m; ++jj) {
            int   s  = __shfl(sidx, jj, 64);
            float w  = __shfl(sc, jj, 64);
            acc = fmaf(h[(long long)s * HDIM + lane], w, acc);
        }
    }
    acc *= inv_in[row];

    float r = 0.0f;
#pragma unroll
    for (int k = 0; k < HDIM; ++k)
        r = fmaf(__shfl(acc, k, 64), Wlds[k * HDIM + lane], r);
    r += bias[lane];
    out[(long long)row * HDIM + lane] = fmaxf(r, 0.0f);
}

extern "C" void kernel_launch(void* const* d_in, const int* in_sizes, int n_in,
                              void* d_out, int out_size, void* d_ws, size_t ws_size,
                              hipStream_t stream) {
    const float* features = (const float*)d_in[0];   // [N, 64]
    const float* W        = (const float*)d_in[1];   // [64, 64]
    const float* b        = (const float*)d_in[2];   // [64]
    const int*   src      = (const int*)d_in[3];     // [E]
    const int*   dst      = (const int*)d_in[4];     // [E]

    float* out = (float*)d_out;                      // [N, 64]

    // workspace layout (4-byte words); total ~34.5 MB
    float* ws      = (float*)d_ws;
    float* inv_out = ws;                               // N
    float* inv_in  = ws + N_NODES;                     // N
    int*   deg_out = (int*)(ws + 2 * N_NODES);         // N
    int*   deg_in  = (int*)(ws + 3 * N_NODES);         // N
    int*   offsets = (int*)(ws + 4 * N_NODES);         // N+1
    int*   cursor  = (int*)(ws + 5 * N_NODES + 1);     // N
    int*   bs      = (int*)(ws + 6 * N_NODES + 1);     // NBLK
    int*   boff    = bs + NBLK;                        // NBLK
    int*   csr_src = boff + NBLK;                      // E
    float* tmp     = (float*)(csr_src + N_EDGES);      // N*H

    const int E = N_EDGES;
    const int N = N_NODES;

    // degrees + norms
    hipMemsetAsync(deg_out, 0, 2 * (size_t)N_NODES * sizeof(int), stream);
    degree_kernel<<<(E + 255) / 256, 256, 0, stream>>>(src, dst, deg_out, deg_in, E);
    invsqrt_kernel<<<(N + 255) / 256, 256, 0, stream>>>(deg_out, deg_in, inv_out, inv_in, N);

    // CSR build (by dst)
    blocksum_kernel<<<NBLK, SCAN_BS, 0, stream>>>(deg_in, bs);
    scan_blocksums<<<1, 512, 0, stream>>>(bs, boff, offsets);
    scan_final<<<NBLK, SCAN_BS, 0, stream>>>(deg_in, boff, offsets, cursor);
    fill_csr<<<(E + 255) / 256, 256, 0, stream>>>(src, dst, cursor, csr_src, E);

    int layer_blocks = (N + 3) / 4;
    // layer 1: features -> tmp
    gcn_layer<<<layer_blocks, 256, 0, stream>>>(features, inv_out, inv_in, offsets, csr_src,
                                                W, b, tmp, N);
    // layer 2: tmp -> out
    gcn_layer<<<layer_blocks, 256, 0, stream>>>(tmp, inv_out, inv_in, offsets, csr_src,
                                                W, b, out, N);
}

// Round 3
// 480.044 us; speedup vs baseline: 2.3471x; 1.4540x over previous
//
#include <hip/hip_runtime.h>

#define N_NODES 100000
#define N_EDGES 1600000
#define HDIM 64
#define SCAN_BS 256
#define NBLK ((N_NODES + SCAN_BS - 1) / SCAN_BS)   // 391

// ---------------- degree computation ----------------
__global__ void degree_kernel(const int* __restrict__ src, const int* __restrict__ dst,
                              int* __restrict__ deg_out, int* __restrict__ deg_in, int E) {
    int e = blockIdx.x * blockDim.x + threadIdx.x;
    if (e < E) {
        atomicAdd(&deg_out[src[e]], 1);
        atomicAdd(&deg_in[dst[e]], 1);
    }
}

__global__ void invsqrt_kernel(const int* __restrict__ deg_out, const int* __restrict__ deg_in,
                               float* __restrict__ inv_out, float* __restrict__ inv_in, int n) {
    int i = blockIdx.x * blockDim.x + threadIdx.x;
    if (i < n) {
        inv_out[i] = rsqrtf((float)max(deg_out[i], 1));
        inv_in[i]  = rsqrtf((float)max(deg_in[i], 1));
    }
}

// ---------------- scan (exclusive prefix sum of deg_in -> CSR offsets) ----------------
__global__ void blocksum_kernel(const int* __restrict__ deg_in, int* __restrict__ bs) {
    int t = threadIdx.x, b = blockIdx.x;
    int i = b * SCAN_BS + t;
    int v = (i < N_NODES) ? deg_in[i] : 0;
    for (int off = 32; off > 0; off >>= 1) v += __shfl_down(v, off, 64);
    __shared__ int w[4];
    if ((t & 63) == 0) w[t >> 6] = v;
    __syncthreads();
    if (t == 0) bs[b] = w[0] + w[1] + w[2] + w[3];
}

__global__ void scan_blocksums(const int* __restrict__ bs, int* __restrict__ boff,
                               int* __restrict__ offsets) {
    __shared__ int s[512];
    int t = threadIdx.x;
    int v = (t < NBLK) ? bs[t] : 0;
    s[t] = v;
    __syncthreads();
    for (int off = 1; off < 512; off <<= 1) {
        int x = (t >= off) ? s[t - off] : 0;
        __syncthreads();
        s[t] += x;
        __syncthreads();
    }
    if (t < NBLK) boff[t] = s[t] - v;
    if (t == 0) offsets[N_NODES] = N_EDGES;
}

__global__ void scan_final(const int* __restrict__ deg_in, const int* __restrict__ boff,
                           int* __restrict__ offsets, int* __restrict__ cursor) {
    __shared__ int s[SCAN_BS];
    int t = threadIdx.x, b = blockIdx.x;
    int i = b * SCAN_BS + t;
    int v = (i < N_NODES) ? deg_in[i] : 0;
    s[t] = v;
    __syncthreads();
    for (int off = 1; off < SCAN_BS; off <<= 1) {
        int x = (t >= off) ? s[t - off] : 0;
        __syncthreads();
        s[t] += x;
        __syncthreads();
    }
    if (i < N_NODES) {
        int excl = s[t] - v + boff[b];
        offsets[i] = excl;
        cursor[i] = excl;
    }
}

// ---------------- CSR fill: csr_src[slot of dst] = src ----------------
__global__ void fill_csr(const int* __restrict__ src, const int* __restrict__ dst,
                         int* __restrict__ cursor, int* __restrict__ csr_src, int E) {
    int e = blockIdx.x * blockDim.x + threadIdx.x;
    if (e < E) {
        int pos = atomicAdd(&cursor[dst[e]], 1);
        csr_src[pos] = src[e];
    }
}

// ---------------- dense: hw = (h * inv_out[:,None]) @ W ----------------
// register-tiled: one block = 64 rows, thread = 4 rows x 4 cols
__global__ void dense_kernel(const float* __restrict__ h, const float* __restrict__ inv_out,
                             const float* __restrict__ W, float* __restrict__ hw, int n) {
    __shared__ float Wlds[HDIM * HDIM];     // 16 KB
    __shared__ float Alds[HDIM][HDIM + 1];  // padded
    int t = threadIdx.x;
    int r0 = blockIdx.x * 64;

    for (int i = t; i < HDIM * HDIM / 4; i += 256)
        ((float4*)Wlds)[i] = ((const float4*)W)[i];

    for (int i = t; i < 1024; i += 256) {   // 64 rows x 16 float4
        int r = i >> 4;
        int c4 = i & 15;
        int row = r0 + r;
        float4 v = make_float4(0.f, 0.f, 0.f, 0.f);
        float s = 0.f;
        if (row < n) {
            v = ((const float4*)h)[(long long)row * 16 + c4];
            s = inv_out[row];
        }
        Alds[r][c4 * 4 + 0] = v.x * s;
        Alds[r][c4 * 4 + 1] = v.y * s;
        Alds[r][c4 * 4 + 2] = v.z * s;
        Alds[r][c4 * 4 + 3] = v.w * s;
    }
    __syncthreads();

    int tx = t & 15;        // col group: cols 4tx..4tx+3
    int ty = t >> 4;        // row group: rows 4ty..4ty+3
    float4 acc0 = make_float4(0.f, 0.f, 0.f, 0.f);
    float4 acc1 = acc0, acc2 = acc0, acc3 = acc0;

#pragma unroll 8
    for (int k = 0; k < HDIM; ++k) {
        float4 w = ((const float4*)(Wlds + k * HDIM))[tx];
        float a0 = Alds[4 * ty + 0][k];
        float a1 = Alds[4 * ty + 1][k];
        float a2 = Alds[4 * ty + 2][k];
        float a3 = Alds[4 * ty + 3][k];
        acc0.x = fmaf(a0, w.x, acc0.x); acc0.y = fmaf(a0, w.y, acc0.y);
        acc0.z = fmaf(a0, w.z, acc0.z); acc0.w = fmaf(a0, w.w, acc0.w);
        acc1.x = fmaf(a1, w.x, acc1.x); acc1.y = fmaf(a1, w.y, acc1.y);
        acc1.z = fmaf(a1, w.z, acc1.z); acc1.w = fmaf(a1, w.w, acc1.w);
        acc2.x = fmaf(a2, w.x, acc2.x); acc2.y = fmaf(a2, w.y, acc2.y);
        acc2.z = fmaf(a2, w.z, acc2.z); acc2.w = fmaf(a2, w.w, acc2.w);
        acc3.x = fmaf(a3, w.x, acc3.x); acc3.y = fmaf(a3, w.y, acc3.y);
        acc3.z = fmaf(a3, w.z, acc3.z); acc3.w = fmaf(a3, w.w, acc3.w);
    }

    int rb = r0 + 4 * ty;
    if (rb + 0 < n) ((float4*)hw)[(long long)(rb + 0) * 16 + tx] = acc0;
    if (rb + 1 < n) ((float4*)hw)[(long long)(rb + 1) * 16 + tx] = acc1;
    if (rb + 2 < n) ((float4*)hw)[(long long)(rb + 2) * 16 + tx] = acc2;
    if (rb + 3 < n) ((float4*)hw)[(long long)(rb + 3) * 16 + tx] = acc3;
}

// ---------------- gather: out = relu(inv_in * sum_{in-edges} hw[src] + b) ----------------
// one wave per dst row; 4 groups of 16 lanes, each group = one edge in flight (float4/lane)
__global__ void gather_kernel(const float* __restrict__ hw, const float* __restrict__ inv_in,
                              const int* __restrict__ offsets, const int* __restrict__ csr_src,
                              const float* __restrict__ bias, float* __restrict__ out, int n) {
    int t = threadIdx.x;
    int wave = t >> 6, lane = t & 63;
    int row = blockIdx.x * 4 + wave;
    if (row >= n) return;
    int group = lane >> 4, gl = lane & 15;

    int start = offsets[row];
    int end   = offsets[row + 1];

    float4 acc = make_float4(0.f, 0.f, 0.f, 0.f);
#pragma unroll 2
    for (int j = start + group; j < end; j += 4) {
        int s = csr_src[j];
        float4 v = ((const float4*)hw)[(long long)s * 16 + gl];
        acc.x += v.x; acc.y += v.y; acc.z += v.z; acc.w += v.w;
    }
    // reduce the 4 group-partials down to group 0
    acc.x += __shfl_down(acc.x, 32, 64);
    acc.y += __shfl_down(acc.y, 32, 64);
    acc.z += __shfl_down(acc.z, 32, 64);
    acc.w += __shfl_down(acc.w, 32, 64);
    acc.x += __shfl_down(acc.x, 16, 64);
    acc.y += __shfl_down(acc.y, 16, 64);
    acc.z += __shfl_down(acc.z, 16, 64);
    acc.w += __shfl_down(acc.w, 16, 64);

    if (group == 0) {
        float sc = inv_in[row];
        float4 b4 = ((const float4*)bias)[gl];
        float4 r;
        r.x = fmaxf(fmaf(acc.x, sc, b4.x), 0.f);
        r.y = fmaxf(fmaf(acc.y, sc, b4.y), 0.f);
        r.z = fmaxf(fmaf(acc.z, sc, b4.z), 0.f);
        r.w = fmaxf(fmaf(acc.w, sc, b4.w), 0.f);
        ((float4*)out)[(long long)row * 16 + gl] = r;
    }
}

extern "C" void kernel_launch(void* const* d_in, const int* in_sizes, int n_in,
                              void* d_out, int out_size, void* d_ws, size_t ws_size,
                              hipStream_t stream) {
    const float* features = (const float*)d_in[0];   // [N, 64]
    const float* W        = (const float*)d_in[1];   // [64, 64]
    const float* b        = (const float*)d_in[2];   // [64]
    const int*   src      = (const int*)d_in[3];     // [E]
    const int*   dst      = (const int*)d_in[4];     // [E]

    float* out = (float*)d_out;                      // [N, 64] — also inter-layer temp

    // workspace layout (4-byte words); ~34.5 MB
    float* ws      = (float*)d_ws;
    float* hw      = ws;                               // N*H (16B-aligned at base)
    float* inv_out = ws + (size_t)N_NODES * HDIM;      // N
    float* inv_in  = inv_out + N_NODES;                // N
    int*   deg_out = (int*)(inv_in + N_NODES);         // N
    int*   deg_in  = deg_out + N_NODES;                // N
    int*   offsets = deg_in + N_NODES;                 // N+1
    int*   cursor  = offsets + N_NODES + 1;            // N
    int*   bs      = cursor + N_NODES;                 // NBLK
    int*   boff    = bs + NBLK;                        // NBLK
    int*   csr_src = boff + NBLK;                      // E

    const int E = N_EDGES;
    const int N = N_NODES;

    // degrees + norms
    hipMemsetAsync(deg_out, 0, 2 * (size_t)N_NODES * sizeof(int), stream);
    degree_kernel<<<(E + 255) / 256, 256, 0, stream>>>(src, dst, deg_out, deg_in, E);
    invsqrt_kernel<<<(N + 255) / 256, 256, 0, stream>>>(deg_out, deg_in, inv_out, inv_in, N);

    // CSR build (by dst)
    blocksum_kernel<<<NBLK, SCAN_BS, 0, stream>>>(deg_in, bs);
    scan_blocksums<<<1, 512, 0, stream>>>(bs, boff, offsets);
    scan_final<<<NBLK, SCAN_BS, 0, stream>>>(deg_in, boff, offsets, cursor);
    fill_csr<<<(E + 255) / 256, 256, 0, stream>>>(src, dst, cursor, csr_src, E);

    int dense_blocks  = (N + 63) / 64;
    int gather_blocks = (N + 3) / 4;

    // layer 1: features -> hw -> out
    dense_kernel<<<dense_blocks, 256, 0, stream>>>(features, inv_out, W, hw, N);
    gather_kernel<<<gather_blocks, 256, 0, stream>>>(hw, inv_in, offsets, csr_src, b, out, N);

    // layer 2: out -> hw -> out
    dense_kernel<<<dense_blocks, 256, 0, stream>>>(out, inv_out, W, hw, N);
    gather_kernel<<<gather_blocks, 256, 0, stream>>>(hw, inv_in, offsets, csr_src, b, out, N);
}